// Round 1
// baseline (144.777 us; speedup 1.0000x reference)
//
#include <hip/hip_runtime.h>
#include <math.h>

// Shapes (fixed by setup_inputs): B=4, Te=512, Td=512, E=256, D+E=512, H=64
#define BB   4
#define TE   512
#define TD   512
#define EE   256
#define DP   512
#define HH   64
#define TDT  4                       // td rows per block in the hot kernel
#define C2L  2.8853900817779268f     // 2*log2(e): tanh(x)=1-2/(2^(C2L*x)+1)
#define LOG2E 1.4426950408889634f

// ---------------------------------------------------------------------------
// Projection: Y[row][h] = C2L * (X[row][:] @ W[:,h] + bias[h])
// One wave per row (64 lanes = 64 h values). X row loads are wave-uniform
// (L1 broadcast); W loads are 256B coalesced per wave.
// ---------------------------------------------------------------------------
__global__ __launch_bounds__(256) void proj_kernel(
    const float* __restrict__ X, const float* __restrict__ W,
    const float* __restrict__ bias, float* __restrict__ Y, int K)
{
    const int h   = threadIdx.x & 63;
    const int row = blockIdx.x * 4 + (threadIdx.x >> 6);
    const float4* xv = reinterpret_cast<const float4*>(X + (size_t)row * K);
    float acc = bias[h];
    #pragma unroll 4
    for (int k4 = 0; k4 < K / 4; ++k4) {
        float4 x = xv[k4];
        int k = k4 * 4;
        acc = fmaf(x.x, W[(k + 0) * HH + h], acc);
        acc = fmaf(x.y, W[(k + 1) * HH + h], acc);
        acc = fmaf(x.z, W[(k + 2) * HH + h], acc);
        acc = fmaf(x.w, W[(k + 3) * HH + h], acc);
    }
    Y[(size_t)row * HH + h] = C2L * acc;
}

// ---------------------------------------------------------------------------
// Fused scores + softmax.
// Block = 512 threads (thread = te), handles TDT=4 td rows of one batch b.
// score[td][te] = b2 + sum_h w2[h]*tanh(dec_t[td][h] + ctx_t[te][h])
//              = (b2 + sum_h w2[h]) + sum_h (-2*w2[h]) / (2^(adec[h]+actx[h]) + 1)
// where adec/actx are the pre-scaled projections.
// ---------------------------------------------------------------------------
__device__ __forceinline__ float wave_rmax(float v) {
    #pragma unroll
    for (int off = 32; off; off >>= 1) v = fmaxf(v, __shfl_xor(v, off));
    return v;
}
__device__ __forceinline__ float wave_rsum(float v) {
    #pragma unroll
    for (int off = 32; off; off >>= 1) v += __shfl_xor(v, off);
    return v;
}

__global__ __launch_bounds__(512) void score_softmax_kernel(
    const float* __restrict__ actx, const float* __restrict__ adec,
    const float* __restrict__ w2, const float* __restrict__ b2p,
    float* __restrict__ out)
{
    __shared__ float sdec[TDT][HH];   // pre-scaled dec rows
    __shared__ float sw2[HH];         // -2 * w2
    __shared__ float sred[TDT][8];    // per-wave partials
    __shared__ float sbase;           // b2 + sum(w2)
    __shared__ float sfin[TDT][2];    // [r][0]=row max, [r][1]=row sum

    const int b    = blockIdx.x >> 7;          // / (TD/TDT)
    const int td0  = (blockIdx.x & 127) * TDT;
    const int tid  = threadIdx.x;
    const int lane = tid & 63;
    const int wid  = tid >> 6;

    if (tid < TDT * HH) {           // 256 threads load 4 dec rows
        int r = tid >> 6, h = tid & 63;
        sdec[r][h] = adec[((size_t)(b * TD + td0 + r)) * HH + h];
    }
    if (tid < HH) {
        float wv = w2[tid];
        sw2[tid] = -2.0f * wv;
        float s = wave_rsum(wv);
        if (tid == 0) sbase = s + b2p[0];
    }
    __syncthreads();

    const int te = tid;
    const float4* cp = reinterpret_cast<const float4*>(
        actx + ((size_t)b * TE + te) * HH);

    float sc[TDT] = {0.f, 0.f, 0.f, 0.f};
    #pragma unroll
    for (int i = 0; i < HH / 4; ++i) {
        float4 c = cp[i];
        const int h = i * 4;
        float w0 = sw2[h], w1 = sw2[h + 1], w2v = sw2[h + 2], w3 = sw2[h + 3];
        #pragma unroll
        for (int r = 0; r < TDT; ++r) {
            float d0 = sdec[r][h], d1 = sdec[r][h + 1];
            float d2 = sdec[r][h + 2], d3 = sdec[r][h + 3];
            float e0 = __builtin_amdgcn_exp2f(d0 + c.x);
            float e1 = __builtin_amdgcn_exp2f(d1 + c.y);
            float e2 = __builtin_amdgcn_exp2f(d2 + c.z);
            float e3 = __builtin_amdgcn_exp2f(d3 + c.w);
            sc[r] = fmaf(w0,  __builtin_amdgcn_rcpf(e0 + 1.0f), sc[r]);
            sc[r] = fmaf(w1,  __builtin_amdgcn_rcpf(e1 + 1.0f), sc[r]);
            sc[r] = fmaf(w2v, __builtin_amdgcn_rcpf(e2 + 1.0f), sc[r]);
            sc[r] = fmaf(w3,  __builtin_amdgcn_rcpf(e3 + 1.0f), sc[r]);
        }
    }

    const float base = sbase;
    float scores[TDT];
    #pragma unroll
    for (int r = 0; r < TDT; ++r) scores[r] = sc[r] + base;

    // ---- row max ----
    #pragma unroll
    for (int r = 0; r < TDT; ++r) {
        float m = wave_rmax(scores[r]);
        if (lane == 0) sred[r][wid] = m;
    }
    __syncthreads();
    if (tid < TDT * 8) {            // 32 threads: 8 partials per row
        int r = tid >> 3;
        float v = sred[r][tid & 7];
        v = fmaxf(v, __shfl_xor(v, 4));
        v = fmaxf(v, __shfl_xor(v, 2));
        v = fmaxf(v, __shfl_xor(v, 1));
        if ((tid & 7) == 0) sfin[r][0] = v;
    }
    __syncthreads();

    // ---- exp + row sum ----
    float ex[TDT];
    #pragma unroll
    for (int r = 0; r < TDT; ++r) {
        ex[r] = __builtin_amdgcn_exp2f((scores[r] - sfin[r][0]) * LOG2E);
        float s = wave_rsum(ex[r]);
        if (lane == 0) sred[r][wid] = s;
    }
    __syncthreads();
    if (tid < TDT * 8) {
        int r = tid >> 3;
        float v = sred[r][tid & 7];
        v += __shfl_xor(v, 4);
        v += __shfl_xor(v, 2);
        v += __shfl_xor(v, 1);
        if ((tid & 7) == 0) sfin[r][1] = v;
    }
    __syncthreads();

    #pragma unroll
    for (int r = 0; r < TDT; ++r) {
        out[((size_t)(b * TD + td0 + r)) * TE + te] = ex[r] / sfin[r][1];
    }
}

// ---------------------------------------------------------------------------
extern "C" void kernel_launch(void* const* d_in, const int* in_sizes, int n_in,
                              void* d_out, int out_size, void* d_ws, size_t ws_size,
                              hipStream_t stream) {
    const float* ctx = (const float*)d_in[0];   // [B, Te, E]
    const float* dec = (const float*)d_in[1];   // [B, Td, D+E]
    const float* W1i = (const float*)d_in[2];   // [E, H]
    const float* b1i = (const float*)d_in[3];   // [H]
    const float* W1h = (const float*)d_in[4];   // [D+E, H]
    const float* b1h = (const float*)d_in[5];   // [H]
    const float* w2  = (const float*)d_in[6];   // [H]
    const float* b2  = (const float*)d_in[7];   // scalar
    float* out = (float*)d_out;                 // [B, Td, Te] f32

    float* actx = (float*)d_ws;                 // B*TE*HH floats (512 KB)
    float* adec = actx + (size_t)BB * TE * HH;  // B*TD*HH floats (512 KB)

    proj_kernel<<<BB * TE / 4, 256, 0, stream>>>(ctx, W1i, b1i, actx, EE);
    proj_kernel<<<BB * TD / 4, 256, 0, stream>>>(dec, W1h, b1h, adec, DP);
    score_softmax_kernel<<<BB * (TD / TDT), 512, 0, stream>>>(
        actx, adec, w2, b2, out);
}

// Round 2
// 110.327 us; speedup vs baseline: 1.3122x; 1.3122x over previous
//
#include <hip/hip_runtime.h>
#include <math.h>

// Shapes (fixed by setup_inputs): B=4, Te=512, Td=512, E=256, D+E=512, H=64
#define BB   4
#define TE   512
#define TD   512
#define EE   256
#define DP   512
#define HH   64
#define TDT  4                       // td rows per block in the hot kernel
#define C2L  2.8853900817779268f     // 2*log2(e): tanh(x)=1-2/(2^(C2L*x)+1)
#define LOG2E 1.4426950408889634f

__device__ __forceinline__ float wave_rmax(float v) {
    #pragma unroll
    for (int off = 32; off; off >>= 1) v = fmaxf(v, __shfl_xor(v, off));
    return v;
}
__device__ __forceinline__ float wave_rsum(float v) {
    #pragma unroll
    for (int off = 32; off; off >>= 1) v += __shfl_xor(v, off);
    return v;
}

// ---------------------------------------------------------------------------
// Merged projections: Y[row][h] = C2L * (X[row][:] @ W[:,h] + bias[h])
// Blocks [0, 512): ctx (K=256). Blocks [512, 1024): dec (K=512).
// One wave per row; 4 independent fma chains to break accumulator latency.
// ---------------------------------------------------------------------------
__global__ __launch_bounds__(256, 4) void proj_kernel(
    const float* __restrict__ Xc, const float* __restrict__ Wc,
    const float* __restrict__ bc,
    const float* __restrict__ Xd, const float* __restrict__ Wd,
    const float* __restrict__ bd,
    float* __restrict__ Yc, float* __restrict__ Yd)
{
    const bool isDec = blockIdx.x >= (BB * TE / 4);
    const float* X    = isDec ? Xd : Xc;
    const float* W    = isDec ? Wd : Wc;
    const float* bias = isDec ? bd : bc;
    float*       Y    = isDec ? Yd : Yc;
    const int    K    = isDec ? DP : EE;
    const int    blk  = isDec ? blockIdx.x - (BB * TE / 4) : blockIdx.x;

    const int h   = threadIdx.x & 63;
    const int row = blk * 4 + (threadIdx.x >> 6);
    const float4* xv = reinterpret_cast<const float4*>(X + (size_t)row * K);
    const float*  Wh = W + h;

    float a0 = 0.f, a1 = 0.f, a2 = 0.f, a3 = 0.f;
    #pragma unroll 4
    for (int k4 = 0; k4 < K / 4; ++k4) {
        float4 x = xv[k4];
        const float* wk = Wh + (size_t)k4 * (4 * HH);
        a0 = fmaf(x.x, wk[0 * HH], a0);
        a1 = fmaf(x.y, wk[1 * HH], a1);
        a2 = fmaf(x.z, wk[2 * HH], a2);
        a3 = fmaf(x.w, wk[3 * HH], a3);
    }
    Y[(size_t)row * HH + h] = C2L * (((a0 + a1) + (a2 + a3)) + bias[h]);
}

// ---------------------------------------------------------------------------
// Fused scores + softmax.
// Block = 512 threads (thread = te), handles TDT=4 td rows of one batch b.
// score[td][te] = (b2 + sum_h w2[h]) + sum_h (-2*w2[h]) / (2^(adec[h]+actx[h]) + 1)
// i-loop kept ROLLED (unroll 2) so the live set stays ~50 VGPRs — the R1
// version fully unrolled and spilled to scratch (90 MB WRITE_SIZE).
// ---------------------------------------------------------------------------
__global__ __launch_bounds__(512, 4) void score_softmax_kernel(
    const float* __restrict__ actx, const float* __restrict__ adec,
    const float* __restrict__ w2, const float* __restrict__ b2p,
    float* __restrict__ out)
{
    __shared__ float sdec[TDT][HH];   // pre-scaled dec rows
    __shared__ float sw2[HH];         // -2 * w2
    __shared__ float sred[TDT][8];    // per-wave partials
    __shared__ float sbase;           // b2 + sum(w2)
    __shared__ float sfin[TDT][2];    // [r][0]=row max, [r][1]=row sum

    const int b    = blockIdx.x >> 7;          // / (TD/TDT)
    const int td0  = (blockIdx.x & 127) * TDT;
    const int tid  = threadIdx.x;
    const int lane = tid & 63;
    const int wid  = tid >> 6;

    if (tid < TDT * HH) {           // 256 threads load 4 dec rows
        int r = tid >> 6, h = tid & 63;
        sdec[r][h] = adec[((size_t)(b * TD + td0 + r)) * HH + h];
    }
    if (tid < HH) {
        float wv = w2[tid];
        sw2[tid] = -2.0f * wv;
        float s = wave_rsum(wv);
        if (tid == 0) sbase = s + b2p[0];
    }
    __syncthreads();

    const int te = tid;
    const float4* cp = reinterpret_cast<const float4*>(
        actx + ((size_t)b * TE + te) * HH);
    const float4* wv4 = reinterpret_cast<const float4*>(sw2);

    float sc0 = 0.f, sc1 = 0.f, sc2 = 0.f, sc3 = 0.f;
    #pragma unroll 2
    for (int i = 0; i < HH / 4; ++i) {
        float4 c  = cp[i];
        float4 w4 = wv4[i];
        #pragma unroll
        for (int r = 0; r < TDT; ++r) {
            float4 d4 = reinterpret_cast<const float4*>(sdec[r])[i];
            float e0 = __builtin_amdgcn_exp2f(d4.x + c.x);
            float e1 = __builtin_amdgcn_exp2f(d4.y + c.y);
            float e2 = __builtin_amdgcn_exp2f(d4.z + c.z);
            float e3 = __builtin_amdgcn_exp2f(d4.w + c.w);
            float v0 = __builtin_amdgcn_rcpf(e0 + 1.0f);
            float v1 = __builtin_amdgcn_rcpf(e1 + 1.0f);
            float v2 = __builtin_amdgcn_rcpf(e2 + 1.0f);
            float v3 = __builtin_amdgcn_rcpf(e3 + 1.0f);
            float t;
            t = fmaf(w4.x, v0, fmaf(w4.y, v1, fmaf(w4.z, v2, w4.w * v3)));
            if (r == 0) sc0 += t;
            else if (r == 1) sc1 += t;
            else if (r == 2) sc2 += t;
            else sc3 += t;
        }
    }

    const float base = sbase;
    float scores[TDT] = { sc0 + base, sc1 + base, sc2 + base, sc3 + base };

    // ---- row max ----
    #pragma unroll
    for (int r = 0; r < TDT; ++r) {
        float m = wave_rmax(scores[r]);
        if (lane == 0) sred[r][wid] = m;
    }
    __syncthreads();
    if (tid < TDT * 8) {            // 32 threads: 8 partials per row
        int r = tid >> 3;
        float v = sred[r][tid & 7];
        v = fmaxf(v, __shfl_xor(v, 4));
        v = fmaxf(v, __shfl_xor(v, 2));
        v = fmaxf(v, __shfl_xor(v, 1));
        if ((tid & 7) == 0) sfin[r][0] = v;
    }
    __syncthreads();

    // ---- exp + row sum ----
    float ex[TDT];
    #pragma unroll
    for (int r = 0; r < TDT; ++r) {
        ex[r] = __builtin_amdgcn_exp2f((scores[r] - sfin[r][0]) * LOG2E);
        float s = wave_rsum(ex[r]);
        if (lane == 0) sred[r][wid] = s;
    }
    __syncthreads();
    if (tid < TDT * 8) {
        int r = tid >> 3;
        float v = sred[r][tid & 7];
        v += __shfl_xor(v, 4);
        v += __shfl_xor(v, 2);
        v += __shfl_xor(v, 1);
        if ((tid & 7) == 0) sfin[r][1] = v;
    }
    __syncthreads();

    #pragma unroll
    for (int r = 0; r < TDT; ++r) {
        float inv = __builtin_amdgcn_rcpf(sfin[r][1]);
        out[((size_t)(b * TD + td0 + r)) * TE + te] = ex[r] * inv;
    }
}

// ---------------------------------------------------------------------------
extern "C" void kernel_launch(void* const* d_in, const int* in_sizes, int n_in,
                              void* d_out, int out_size, void* d_ws, size_t ws_size,
                              hipStream_t stream) {
    const float* ctx = (const float*)d_in[0];   // [B, Te, E]
    const float* dec = (const float*)d_in[1];   // [B, Td, D+E]
    const float* W1i = (const float*)d_in[2];   // [E, H]
    const float* b1i = (const float*)d_in[3];   // [H]
    const float* W1h = (const float*)d_in[4];   // [D+E, H]
    const float* b1h = (const float*)d_in[5];   // [H]
    const float* w2  = (const float*)d_in[6];   // [H]
    const float* b2  = (const float*)d_in[7];   // scalar
    float* out = (float*)d_out;                 // [B, Td, Te] f32

    float* actx = (float*)d_ws;                 // B*TE*HH floats (512 KB)
    float* adec = actx + (size_t)BB * TE * HH;  // B*TD*HH floats (512 KB)

    proj_kernel<<<BB * TE / 4 + BB * TD / 4, 256, 0, stream>>>(
        ctx, W1i, b1i, dec, W1h, b1h, actx, adec);
    score_softmax_kernel<<<BB * (TD / TDT), 512, 0, stream>>>(
        actx, adec, w2, b2, out);
}

// Round 5
// 103.786 us; speedup vs baseline: 1.3950x; 1.0630x over previous
//
#include <hip/hip_runtime.h>
#include <math.h>

// Shapes (fixed by setup_inputs): B=4, Te=512, Td=512, E=256, D+E=512, H=64
#define BB   4
#define TE   512
#define TD   512
#define EE   256
#define DP   512
#define HH   64
#define TDT  4                       // td rows per block in the score kernel
#define RPW  4                       // rows per proj block (W-reuse factor)
#define C2L  2.8853900817779268f     // 2*log2(e): tanh(x)=1-2/(2^(C2L*x)+1)
#define LOG2E 1.4426950408889634f

#define NB_CTX (BB * TE / RPW)       // 512 proj blocks for ctx
#define NB_DEC (BB * TD / RPW)       // 512 proj blocks for dec

__device__ __forceinline__ float wave_rmax(float v) {
    #pragma unroll
    for (int off = 32; off; off >>= 1) v = fmaxf(v, __shfl_xor(v, off));
    return v;
}
__device__ __forceinline__ float wave_rsum(float v) {
    #pragma unroll
    for (int off = 32; off; off >>= 1) v += __shfl_xor(v, off);
    return v;
}

// ---------------------------------------------------------------------------
// Merged projections, restructured for W reuse:
//   - each block computes RPW=4 rows; W values are loaded once per 4 rows
//     (W traffic 384 MB -> 96 MB, the R2 bottleneck)
//   - the block's 4 waves split K 4-ways (keeps 4096 waves = 4/SIMD)
//   - partials combined through LDS
// ctx output is written TRANSPOSED: actxT[b][h][te], so the score kernel's
// per-te loads are coalesced. dec output stays [row][h] (broadcast via LDS).
// Both outputs are pre-scaled by C2L.
// ---------------------------------------------------------------------------
__global__ __launch_bounds__(256, 4) void proj_kernel(
    const float* __restrict__ Xc, const float* __restrict__ Wc,
    const float* __restrict__ bc,
    const float* __restrict__ Xd, const float* __restrict__ Wd,
    const float* __restrict__ bd,
    float* __restrict__ actxT, float* __restrict__ adec)
{
    __shared__ float part[4][RPW][HH];   // [k-split wave][row][h]

    const bool  isDec = blockIdx.x >= NB_CTX;
    const int   blk   = isDec ? (int)blockIdx.x - NB_CTX : (int)blockIdx.x;
    const float* X    = isDec ? Xd : Xc;
    const float* W    = isDec ? Wd : Wc;
    const float* bias = isDec ? bd : bc;
    const int   K     = isDec ? DP : EE;

    const int Kw   = K >> 2;             // K chunk per wave
    const int lane = threadIdx.x & 63;
    const int wid  = threadIdx.x >> 6;
    const int r0   = blk * RPW;
    const int kb   = wid * Kw;

    const float*  Wl = W + (size_t)kb * HH + lane;
    const float4* x0 = reinterpret_cast<const float4*>(X + (size_t)(r0+0)*K + kb);
    const float4* x1 = reinterpret_cast<const float4*>(X + (size_t)(r0+1)*K + kb);
    const float4* x2 = reinterpret_cast<const float4*>(X + (size_t)(r0+2)*K + kb);
    const float4* x3 = reinterpret_cast<const float4*>(X + (size_t)(r0+3)*K + kb);

    float a0 = 0.f, a1 = 0.f, a2 = 0.f, a3 = 0.f;
    const int niter = Kw >> 2;
    #pragma unroll 4
    for (int k4 = 0; k4 < niter; ++k4) {
        const float* wk = Wl + (size_t)k4 * (4 * HH);
        float w0 = wk[0 * HH], w1 = wk[1 * HH], w2v = wk[2 * HH], w3 = wk[3 * HH];
        float4 v0 = x0[k4], v1 = x1[k4], v2 = x2[k4], v3 = x3[k4];
        a0 = fmaf(v0.x, w0, fmaf(v0.y, w1, fmaf(v0.z, w2v, fmaf(v0.w, w3, a0))));
        a1 = fmaf(v1.x, w0, fmaf(v1.y, w1, fmaf(v1.z, w2v, fmaf(v1.w, w3, a1))));
        a2 = fmaf(v2.x, w0, fmaf(v2.y, w1, fmaf(v2.z, w2v, fmaf(v2.w, w3, a2))));
        a3 = fmaf(v3.x, w0, fmaf(v3.y, w1, fmaf(v3.z, w2v, fmaf(v3.w, w3, a3))));
    }
    part[wid][0][lane] = a0;
    part[wid][1][lane] = a1;
    part[wid][2][lane] = a2;
    part[wid][3][lane] = a3;
    __syncthreads();

    if (isDec) {
        // coalesced [row][h] store
        int r = threadIdx.x >> 6, h = threadIdx.x & 63;
        float s = part[0][r][h] + part[1][r][h] + part[2][r][h] + part[3][r][h];
        adec[(size_t)(r0 + r) * HH + h] = C2L * (s + bias[h]);
    } else {
        // transposed store actxT[b][h][te] in 16B segments (h = tid>>2, r = tid&3)
        int h = threadIdx.x >> 2, r = threadIdx.x & 3;
        float s = part[0][r][h] + part[1][r][h] + part[2][r][h] + part[3][r][h];
        int row = r0 + r;
        int b = row >> 9, te = row & 511;
        actxT[((size_t)b * HH + h) * TE + te] = C2L * (s + bias[h]);
    }
}

// ---------------------------------------------------------------------------
// Fused scores + softmax.  Block = 512 threads (thread = te), TDT=4 td rows.
// score = (b2 + sum w2) + sum_h (-2*w2[h]) / (2^(adec[h]+actxT[h][te]) + 1)
// actxT reads are now coalesced dwords (lane = consecutive te).
// ---------------------------------------------------------------------------
__global__ __launch_bounds__(512, 4) void score_softmax_kernel(
    const float* __restrict__ actxT, const float* __restrict__ adec,
    const float* __restrict__ w2, const float* __restrict__ b2p,
    float* __restrict__ out)
{
    __shared__ float4 sdec4[TDT][HH / 4];  // pre-scaled dec rows
    __shared__ float4 sw24[HH / 4];        // -2 * w2
    __shared__ float  sred[TDT][8];
    __shared__ float  sbase;
    __shared__ float  sfin[TDT][2];        // [r][0]=max, [r][1]=sum

    const int b    = blockIdx.x >> 7;
    const int td0  = (blockIdx.x & 127) * TDT;
    const int tid  = threadIdx.x;
    const int lane = tid & 63;
    const int wid  = tid >> 6;

    if (tid < TDT * HH) {
        int r = tid >> 6, h = tid & 63;
        reinterpret_cast<float*>(&sdec4[r][0])[h] =
            adec[(size_t)(b * TD + td0 + r) * HH + h];
    }
    if (tid < HH) {
        float wv = w2[tid];
        reinterpret_cast<float*>(sw24)[tid] = -2.0f * wv;
        float s = wave_rsum(wv);
        if (tid == 0) sbase = s + b2p[0];
    }
    __syncthreads();

    const int te = tid;
    const float* cT = actxT + (size_t)b * HH * TE + te;

    float sc0 = 0.f, sc1 = 0.f, sc2 = 0.f, sc3 = 0.f;
    #pragma unroll 2
    for (int h4 = 0; h4 < HH / 4; ++h4) {
        const float* cp = cT + (size_t)h4 * (4 * TE);
        float c0 = cp[0 * TE], c1 = cp[1 * TE], c2 = cp[2 * TE], c3 = cp[3 * TE];
        float4 w4 = sw24[h4];
        #pragma unroll
        for (int r = 0; r < TDT; ++r) {
            float4 d4 = sdec4[r][h4];
            float e0 = __builtin_amdgcn_exp2f(d4.x + c0);
            float e1 = __builtin_amdgcn_exp2f(d4.y + c1);
            float e2 = __builtin_amdgcn_exp2f(d4.z + c2);
            float e3 = __builtin_amdgcn_exp2f(d4.w + c3);
            float t = fmaf(w4.x, __builtin_amdgcn_rcpf(e0 + 1.0f),
                      fmaf(w4.y, __builtin_amdgcn_rcpf(e1 + 1.0f),
                      fmaf(w4.z, __builtin_amdgcn_rcpf(e2 + 1.0f),
                           w4.w * __builtin_amdgcn_rcpf(e3 + 1.0f))));
            if      (r == 0) sc0 += t;
            else if (r == 1) sc1 += t;
            else if (r == 2) sc2 += t;
            else             sc3 += t;
        }
    }

    const float base = sbase;
    float scores[TDT] = { sc0 + base, sc1 + base, sc2 + base, sc3 + base };

    // ---- row max ----
    #pragma unroll
    for (int r = 0; r < TDT; ++r) {
        float m = wave_rmax(scores[r]);
        if (lane == 0) sred[r][wid] = m;
    }
    __syncthreads();
    if (tid < TDT * 8) {
        int r = tid >> 3;
        float v = sred[r][tid & 7];
        v = fmaxf(v, __shfl_xor(v, 4));
        v = fmaxf(v, __shfl_xor(v, 2));
        v = fmaxf(v, __shfl_xor(v, 1));
        if ((tid & 7) == 0) sfin[r][0] = v;
    }
    __syncthreads();

    // ---- exp + row sum ----
    float ex[TDT];
    #pragma unroll
    for (int r = 0; r < TDT; ++r) {
        ex[r] = __builtin_amdgcn_exp2f((scores[r] - sfin[r][0]) * LOG2E);
        float s = wave_rsum(ex[r]);
        if (lane == 0) sred[r][wid] = s;
    }
    __syncthreads();
    if (tid < TDT * 8) {
        int r = tid >> 3;
        float v = sred[r][tid & 7];
        v += __shfl_xor(v, 4);
        v += __shfl_xor(v, 2);
        v += __shfl_xor(v, 1);
        if ((tid & 7) == 0) sfin[r][1] = v;
    }
    __syncthreads();

    #pragma unroll
    for (int r = 0; r < TDT; ++r) {
        float inv = __builtin_amdgcn_rcpf(sfin[r][1]);
        out[((size_t)(b * TD + td0 + r)) * TE + te] = ex[r] * inv;
    }
}

// ---------------------------------------------------------------------------
extern "C" void kernel_launch(void* const* d_in, const int* in_sizes, int n_in,
                              void* d_out, int out_size, void* d_ws, size_t ws_size,
                              hipStream_t stream) {
    const float* ctx = (const float*)d_in[0];   // [B, Te, E]
    const float* dec = (const float*)d_in[1];   // [B, Td, D+E]
    const float* W1i = (const float*)d_in[2];   // [E, H]
    const float* b1i = (const float*)d_in[3];   // [H]
    const float* W1h = (const float*)d_in[4];   // [D+E, H]
    const float* b1h = (const float*)d_in[5];   // [H]
    const float* w2  = (const float*)d_in[6];   // [H]
    const float* b2  = (const float*)d_in[7];   // scalar
    float* out = (float*)d_out;                 // [B, Td, Te] f32

    float* actxT = (float*)d_ws;                 // [B][H][TE] floats (512 KB)
    float* adec  = actxT + (size_t)BB * HH * TE; // [B*TD][H] floats (512 KB)

    proj_kernel<<<NB_CTX + NB_DEC, 256, 0, stream>>>(
        ctx, W1i, b1i, dec, W1h, b1h, actxT, adec);
    score_softmax_kernel<<<BB * (TD / TDT), 512, 0, stream>>>(
        actxT, adec, w2, b2, out);
}